// Round 2
// baseline (1923.428 us; speedup 1.0000x reference)
//
#include <hip/hip_runtime.h>
#include <math.h>

constexpr int HID    = 64;
constexpr int TT     = 2048;
constexpr int NHEAD  = 8;
constexpr int TDENSE = 512;
constexpr int ZC     = 1032;   // 2*k_budget + 8
constexpr int BITW   = 1024;   // 32768 bits -> pixel values < 32768

__device__ __forceinline__ float waveSum(float v) {
#pragma unroll
    for (int o = 32; o > 0; o >>= 1) v += __shfl_xor(v, o, 64);
    return v;
}
__device__ __forceinline__ int waveSumI(int v) {
#pragma unroll
    for (int o = 32; o > 0; o >>= 1) v += __shfl_xor(v, o, 64);
    return v;
}
__device__ __forceinline__ float waveMax(float v) {
#pragma unroll
    for (int o = 32; o > 0; o >>= 1) v = fmaxf(v, __shfl_xor(v, o, 64));
    return v;
}
// order-preserving f32 -> u32 (ascending)
__device__ __forceinline__ unsigned orderKey(float f) {
    unsigned u = __float_as_uint(f);
    return (u & 0x80000000u) ? ~u : (u | 0x80000000u);
}
__device__ __forceinline__ float dot4(float4 a, float4 b) {
    return fmaf(a.x, b.x, fmaf(a.y, b.y, fmaf(a.z, b.z, a.w * b.w)));
}
// reduce within 16-lane group (xor 1,2,4,8)
__device__ __forceinline__ float grpSum16(float s) {
#pragma unroll
    for (int o = 1; o <= 8; o <<= 1) s += __shfl_xor(s, o, 64);
    return s;
}

struct __align__(16) SMem {
    float qf[HID];          // query row
    float aq[HID];          // |q|
    float qm[HID];          // SPARQ-masked q
    float partial[256];     // PV partials, [wave][dim]
    unsigned short pixA[ZC];
    unsigned short pixB[ZC];
    unsigned skey[ZC];      // score keys; reused as float qk[] in attention
    unsigned bitmap[BITW];
    unsigned hist[256];
    float red[8];
    int scal[8];
    unsigned wsum[4];
};

__global__ __launch_bounds__(256)
void tree_attn_kernel(const float* __restrict__ q, const float* __restrict__ k,
                      const float* __restrict__ v, float* __restrict__ out) {
    __shared__ SMem sm;
    const int t    = blockIdx.x;      // global query row 0..2047
    const int h    = blockIdx.y;      // head
    const int tid  = threadIdx.x;
    const int lane = tid & 63;
    const int wave = tid >> 6;
    const int sub  = lane & 15;       // dim quad within group
    const int grp  = lane >> 4;       // candidate slot within wave

    const float* qrow = q + (size_t)(h * TT + t) * HID;
    const float* kh   = k + (size_t)h * TT * HID;
    const float* vh   = v + (size_t)h * TT * HID;
    float*       orow = out + (size_t)(h * TT + t) * HID;

    if (tid < HID) sm.qf[tid] = qrow[tid];
    __syncthreads();

    if (t < TDENSE) {
        // ---------------- dense causal attention: keys 0..t ----------------
        const int nk = t + 1;
        float* f = (float*)sm.skey;
        const float4 qfv = reinterpret_cast<const float4*>(sm.qf)[sub];
        for (int z = (wave << 2) + grp; z < nk; z += 16) {
            const float4 kv = *reinterpret_cast<const float4*>(kh + (size_t)z * HID + (sub << 2));
            float s = grpSum16(dot4(kv, qfv));
            if (sub == 0) f[z] = s;
        }
        __syncthreads();
        float m = -3.0e38f;
        for (int z = tid; z < nk; z += 256) m = fmaxf(m, f[z]);
        m = waveMax(m);
        if (lane == 0) sm.red[wave] = m;
        __syncthreads();
        m = fmaxf(fmaxf(sm.red[0], sm.red[1]), fmaxf(sm.red[2], sm.red[3]));
        __syncthreads();
        float ls = 0.f;
        for (int z = tid; z < nk; z += 256) { float e = expf(f[z] - m); f[z] = e; ls += e; }
        ls = waveSum(ls);
        if (lane == 0) sm.red[4 + wave] = ls;
        __syncthreads();
        ls = sm.red[4] + sm.red[5] + sm.red[6] + sm.red[7];
        float4 acc = {0.f, 0.f, 0.f, 0.f};
        for (int z = (wave << 2) + grp; z < nk; z += 16) {
            float w = f[z];
            const float4 vv = *reinterpret_cast<const float4*>(vh + (size_t)z * HID + (sub << 2));
            acc.x = fmaf(w, vv.x, acc.x); acc.y = fmaf(w, vv.y, acc.y);
            acc.z = fmaf(w, vv.z, acc.z); acc.w = fmaf(w, vv.w, acc.w);
        }
#pragma unroll
        for (int o = 16; o <= 32; o <<= 1) {
            acc.x += __shfl_xor(acc.x, o, 64); acc.y += __shfl_xor(acc.y, o, 64);
            acc.z += __shfl_xor(acc.z, o, 64); acc.w += __shfl_xor(acc.w, o, 64);
        }
        if (grp == 0) reinterpret_cast<float4*>(sm.partial)[wave * 16 + sub] = acc;
        __syncthreads();
        if (tid < HID) {
            float o = sm.partial[tid] + sm.partial[64 + tid] + sm.partial[128 + tid] + sm.partial[192 + tid];
            orow[tid] = o / ls;
        }
        return;
    }

    // ---------------- sparse rows: forward_mask + attention ----------------
    const int a     = t - TDENSE;
    const int tsrci = TDENSE + 1 + a;       // 513 + a  (causal key count)
    const float tsrc = (float)tsrci;

    // top-32 |q| dims (stable ties -> lower index), matching jax.lax.top_k
    if (tid < HID) sm.aq[tid] = fabsf(sm.qf[tid]);
    __syncthreads();
    if (tid < HID) {
        float me = sm.aq[tid]; int c = 0;
#pragma unroll
        for (int i = 0; i < HID; i++) {
            float o = sm.aq[i];
            c += (o > me) || (o == me && i < tid);
        }
        sm.qm[tid] = (c < 32) ? sm.qf[tid] : 0.0f;
    }
    // initial state: pixels = z<512 ? z : 0 ; valid prefix U=64
    for (int z = tid; z < ZC; z += 256) sm.pixA[z] = (z < 512) ? (unsigned short)z : (unsigned short)0;
    __syncthreads();

    const float4 qmv = reinterpret_cast<const float4*>(sm.qm)[sub];

    unsigned short* cur = sm.pixA;
    unsigned short* nxt = sm.pixB;
    int U = 64;
    float ws = 64.0f;

    for (int it = 0; it < 6; it++) {
        if (ws == tsrc) break;                       // scale==1 iterations are state no-ops
        const float wsn   = fminf(tsrc, ws * 2.0f);  // ws_new
        const float ratio = tsrc / ws;               // tsrcs_f / ws (fp32, as in ref)

        // ---- scores for valid candidates (quad-dot: 4 candidates/wave/trip) ----
        for (int z = (wave << 2) + grp; z < U; z += 16) {
            int p  = cur[z];
            int tx = (int)rintf((float)p * ratio);
            tx = min(max(tx, 0), TT - 1);
            const float4 kv = *reinterpret_cast<const float4*>(kh + (size_t)tx * HID + (sub << 2));
            float s = grpSum16(dot4(kv, qmv));
            if (sub == 0) sm.skey[z] = orderKey(s);
        }
        // tks = clip(round(ws/tsrc*512), 1, min(ws-1, 1031))
        float tkf = rintf((ws / tsrc) * 512.0f);
        tkf = fminf(fmaxf(tkf, 1.0f), fminf(ws - 1.0f, 1031.0f));
        const int tks = (int)tkf;
        __syncthreads();

        // ---- threshold = tks-th largest score (radix select, MSB->LSB) ----
        unsigned thr = 0u;                           // tks >= U -> select all
        if (tks < U) {
            if (tid == 0) { sm.scal[0] = tks; sm.scal[1] = 0; }
            __syncthreads();
            for (int bs = 24; bs >= 0; bs -= 8) {
                sm.hist[tid] = 0;
                __syncthreads();
                unsigned pref = (unsigned)sm.scal[1];
                for (int z = tid; z < U; z += 256) {
                    unsigned key = sm.skey[z];
                    bool ok = (bs == 24) || ((key >> (bs + 8)) == (pref >> (bs + 8)));
                    if (ok) atomicAdd(&sm.hist[(key >> bs) & 255u], 1u);
                }
                __syncthreads();
                if (tid == 0) {
                    unsigned want = (unsigned)sm.scal[0];
                    int b = 255;
                    for (; b > 0; b--) {
                        unsigned c = sm.hist[b];
                        if (want <= c) break;
                        want -= c;
                    }
                    sm.scal[0] = (int)want;
                    sm.scal[1] = (int)(pref | ((unsigned)b << bs));
                }
                __syncthreads();
            }
            thr = (unsigned)sm.scal[1];
        }

        // ---- subdivision into bitmap (sort+unique+truncate == ascending bits) ----
        const float scale = wsn / ws;
        for (int w0 = tid; w0 < BITW; w0 += 256) sm.bitmap[w0] = 0;
        __syncthreads();
        for (int z = tid; z < ZC; z += 256) {
            int p = cur[z];
            float pf = (float)p;
            int ps0 = (int)rintf(pf * scale);
            ps0 = min(ps0, 32767);
            atomicOr(&sm.bitmap[ps0 >> 5], 1u << (ps0 & 31));
            if (z < U && sm.skey[z] >= thr) {        // selected -> second child when counts>=2
                int ps1 = (int)rintf((pf + 1.0f) * scale);
                if (ps1 - ps0 >= 2) {
                    int ch = min(ps0 + 1, 32767);
                    atomicOr(&sm.bitmap[ch >> 5], 1u << (ch & 31));
                }
            }
        }
        __syncthreads();

        // ---- compact bitmap -> ascending unique list, capped at ZC ----
        const int base = tid * 4;
        int myc = 0;
#pragma unroll
        for (int w0 = 0; w0 < 4; w0++) myc += __popc(sm.bitmap[base + w0]);
        int x = myc;
#pragma unroll
        for (int o = 1; o < 64; o <<= 1) {
            int y = __shfl_up(x, o, 64);
            if (lane >= o) x += y;
        }
        if (lane == 63) sm.wsum[wave] = (unsigned)x;
        __syncthreads();
        int wOff = 0;
        for (int wv = 0; wv < wave; wv++) wOff += (int)sm.wsum[wv];
        const int total = (int)(sm.wsum[0] + sm.wsum[1] + sm.wsum[2] + sm.wsum[3]);
        const int newU = min(total, ZC);
        int pos = wOff + x - myc;
#pragma unroll
        for (int w0 = 0; w0 < 4; w0++) {
            unsigned bits = sm.bitmap[base + w0];
            int vbase = (base + w0) << 5;
            while (bits) {
                int b = __ffs(bits) - 1;
                bits &= bits - 1;
                if (pos < ZC) nxt[pos] = (unsigned short)(vbase + b);
                pos++;
            }
        }
        for (int z = newU + tid; z < ZC; z += 256) nxt[z] = 0;
        __syncthreads();

        unsigned short* tmp = cur; cur = nxt; nxt = tmp;
        U = newU;
        ws = wsn;
    }

    // ---- attended keys = prefix of cur with value < tsrc (ascending list) ----
    int ca = 0;
    for (int z = tid; z < U; z += 256) ca += (cur[z] < tsrci) ? 1 : 0;
    ca = waveSumI(ca);
    if (lane == 0) sm.scal[wave] = ca;
    __syncthreads();
    const int Uatt = sm.scal[0] + sm.scal[1] + sm.scal[2] + sm.scal[3];
    __syncthreads();

    float* f = (float*)sm.skey;
    const float4 qfv = reinterpret_cast<const float4*>(sm.qf)[sub];
    for (int z = (wave << 2) + grp; z < Uatt; z += 16) {
        const float4 kv = *reinterpret_cast<const float4*>(kh + (size_t)cur[z] * HID + (sub << 2));
        float s = grpSum16(dot4(kv, qfv));
        if (sub == 0) f[z] = s;
    }
    __syncthreads();
    float m = -3.0e38f;
    for (int z = tid; z < Uatt; z += 256) m = fmaxf(m, f[z]);
    m = waveMax(m);
    if (lane == 0) sm.red[wave] = m;
    __syncthreads();
    m = fmaxf(fmaxf(sm.red[0], sm.red[1]), fmaxf(sm.red[2], sm.red[3]));
    __syncthreads();
    float ls = 0.f;
    for (int z = tid; z < Uatt; z += 256) { float e = expf(f[z] - m); f[z] = e; ls += e; }
    ls = waveSum(ls);
    if (lane == 0) sm.red[4 + wave] = ls;
    __syncthreads();
    ls = sm.red[4] + sm.red[5] + sm.red[6] + sm.red[7];
    float4 acc = {0.f, 0.f, 0.f, 0.f};
    for (int z = (wave << 2) + grp; z < Uatt; z += 16) {
        float w = f[z];
        const float4 vv = *reinterpret_cast<const float4*>(vh + (size_t)cur[z] * HID + (sub << 2));
        acc.x = fmaf(w, vv.x, acc.x); acc.y = fmaf(w, vv.y, acc.y);
        acc.z = fmaf(w, vv.z, acc.z); acc.w = fmaf(w, vv.w, acc.w);
    }
#pragma unroll
    for (int o = 16; o <= 32; o <<= 1) {
        acc.x += __shfl_xor(acc.x, o, 64); acc.y += __shfl_xor(acc.y, o, 64);
        acc.z += __shfl_xor(acc.z, o, 64); acc.w += __shfl_xor(acc.w, o, 64);
    }
    if (grp == 0) reinterpret_cast<float4*>(sm.partial)[wave * 16 + sub] = acc;
    __syncthreads();
    if (tid < HID) {
        float o = sm.partial[tid] + sm.partial[64 + tid] + sm.partial[128 + tid] + sm.partial[192 + tid];
        orow[tid] = o / ls;
    }
}

extern "C" void kernel_launch(void* const* d_in, const int* in_sizes, int n_in,
                              void* d_out, int out_size, void* d_ws, size_t ws_size,
                              hipStream_t stream) {
    (void)in_sizes; (void)n_in; (void)d_ws; (void)ws_size; (void)out_size;
    const float* q = (const float*)d_in[0];
    const float* k = (const float*)d_in[1];
    const float* v = (const float*)d_in[2];
    // d_in[3] = mask: analytically causal, not needed
    float* out = (float*)d_out;
    dim3 grid(TT, NHEAD);
    tree_attn_kernel<<<grid, 256, 0, stream>>>(q, k, v, out);
}

// Round 6
// 1170.841 us; speedup vs baseline: 1.6428x; 1.6428x over previous
//
#include <hip/hip_runtime.h>
#include <math.h>

constexpr int HID    = 64;
constexpr int TT     = 2048;
constexpr int NHEAD  = 8;
constexpr int TDENSE = 512;
constexpr int ZC     = 1032;   // 2*k_budget + 8
constexpr int BITW   = 1024;   // 32768 bits -> pixel values < 32768

__device__ __forceinline__ float waveSum(float v) {
#pragma unroll
    for (int o = 32; o > 0; o >>= 1) v += __shfl_xor(v, o, 64);
    return v;
}
__device__ __forceinline__ int waveSumI(int v) {
#pragma unroll
    for (int o = 32; o > 0; o >>= 1) v += __shfl_xor(v, o, 64);
    return v;
}
__device__ __forceinline__ float waveMax(float v) {
#pragma unroll
    for (int o = 32; o > 0; o >>= 1) v = fmaxf(v, __shfl_xor(v, o, 64));
    return v;
}
// order-preserving f32 -> u32 (ascending)
__device__ __forceinline__ unsigned orderKey(float f) {
    unsigned u = __float_as_uint(f);
    return (u & 0x80000000u) ? ~u : (u | 0x80000000u);
}
__device__ __forceinline__ float dot4(float4 a, float4 b) {
    return fmaf(a.x, b.x, fmaf(a.y, b.y, fmaf(a.z, b.z, a.w * b.w)));
}
// full 64-dim dot: K row (global, own row per thread) x q (LDS broadcast)
__device__ __forceinline__ float dotRow64(const float4* __restrict__ kr,
                                          const float4* __restrict__ qs) {
    float s0 = 0.f, s1 = 0.f, s2 = 0.f, s3 = 0.f;
#pragma unroll 2
    for (int i = 0; i < 4; i++) {
        float4 ka = kr[4*i+0], kb = kr[4*i+1], kc = kr[4*i+2], kd = kr[4*i+3];
        float4 qa = qs[4*i+0], qb = qs[4*i+1], qc = qs[4*i+2], qd = qs[4*i+3];
        s0 += dot4(ka, qa); s1 += dot4(kb, qb);
        s2 += dot4(kc, qc); s3 += dot4(kd, qd);
    }
    return (s0 + s1) + (s2 + s3);
}

struct __align__(16) SMem {
    float qf[HID];          // query row
    float aq[HID];          // |q|
    float qm[HID];          // SPARQ-masked q
    float partial[256];     // PV partials, [wave][dim]
    unsigned short pixA[ZC];
    unsigned short pixB[ZC];
    unsigned skey[ZC];      // score keys; reused as float qk[] in attention
    unsigned bitmap[BITW];
    unsigned hist[256];
    float red[8];
    int scal[8];
    unsigned wsum[4];
};

__global__ __launch_bounds__(256)
void tree_attn_kernel(const float* __restrict__ q, const float* __restrict__ k,
                      const float* __restrict__ v, float* __restrict__ out) {
    __shared__ SMem sm;
    const int t    = blockIdx.x;      // global query row 0..2047
    const int h    = blockIdx.y;      // head
    const int tid  = threadIdx.x;
    const int lane = tid & 63;
    const int wave = tid >> 6;
    const int sub  = lane & 15;       // dim quad within group (PV)
    const int grp  = lane >> 4;       // row slot within wave (PV)

    const float* qrow = q + (size_t)(h * TT + t) * HID;
    const float* kh   = k + (size_t)h * TT * HID;
    const float* vh   = v + (size_t)h * TT * HID;
    float*       orow = out + (size_t)(h * TT + t) * HID;

    if (tid < HID) sm.qf[tid] = qrow[tid];
    __syncthreads();

    if (t < TDENSE) {
        // ---------------- dense causal attention: keys 0..t ----------------
        const int nk = t + 1;
        float* f = (float*)sm.skey;
        for (int z = tid; z < nk; z += 256)
            f[z] = dotRow64((const float4*)(kh + (size_t)z * HID), (const float4*)sm.qf);
        __syncthreads();
        float m = -3.0e38f;
        for (int z = tid; z < nk; z += 256) m = fmaxf(m, f[z]);
        m = waveMax(m);
        if (lane == 0) sm.red[wave] = m;
        __syncthreads();
        m = fmaxf(fmaxf(sm.red[0], sm.red[1]), fmaxf(sm.red[2], sm.red[3]));
        __syncthreads();
        float ls = 0.f;
        for (int z = tid; z < nk; z += 256) { float e = expf(f[z] - m); f[z] = e; ls += e; }
        ls = waveSum(ls);
        if (lane == 0) sm.red[4 + wave] = ls;
        __syncthreads();
        ls = sm.red[4] + sm.red[5] + sm.red[6] + sm.red[7];
        float4 acc = {0.f, 0.f, 0.f, 0.f};
        for (int z = (wave << 2) + grp; z < nk; z += 16) {
            float w = f[z];
            const float4 vv = *reinterpret_cast<const float4*>(vh + (size_t)z * HID + (sub << 2));
            acc.x = fmaf(w, vv.x, acc.x); acc.y = fmaf(w, vv.y, acc.y);
            acc.z = fmaf(w, vv.z, acc.z); acc.w = fmaf(w, vv.w, acc.w);
        }
#pragma unroll
        for (int o = 16; o <= 32; o <<= 1) {
            acc.x += __shfl_xor(acc.x, o, 64); acc.y += __shfl_xor(acc.y, o, 64);
            acc.z += __shfl_xor(acc.z, o, 64); acc.w += __shfl_xor(acc.w, o, 64);
        }
        if (grp == 0) reinterpret_cast<float4*>(sm.partial)[wave * 16 + sub] = acc;
        __syncthreads();
        if (tid < HID) {
            float o = sm.partial[tid] + sm.partial[64 + tid] + sm.partial[128 + tid] + sm.partial[192 + tid];
            orow[tid] = o / ls;
        }
        return;
    }

    // ---------------- sparse rows: forward_mask + attention ----------------
    const int a     = t - TDENSE;
    const int tsrci = TDENSE + 1 + a;       // 513 + a  (causal key count)
    const float tsrc = (float)tsrci;

    // top-32 |q| dims (stable ties -> lower index), matching jax.lax.top_k
    if (tid < HID) sm.aq[tid] = fabsf(sm.qf[tid]);
    __syncthreads();
    if (tid < HID) {
        float me = sm.aq[tid]; int c = 0;
#pragma unroll
        for (int i = 0; i < HID; i++) {
            float o = sm.aq[i];
            c += (o > me) || (o == me && i < tid);
        }
        sm.qm[tid] = (c < 32) ? sm.qf[tid] : 0.0f;
    }
    // initial state: pixels = z<512 ? z : 0 ; valid prefix U=64
    for (int z = tid; z < ZC; z += 256) sm.pixA[z] = (z < 512) ? (unsigned short)z : (unsigned short)0;
    __syncthreads();

    unsigned short* cur = sm.pixA;
    unsigned short* nxt = sm.pixB;
    int U = 64;
    float ws = 64.0f;
    int pmaxb = 511;                        // upper bound on any pixel value in cur

    for (int it = 0; it < 6; it++) {
        if (ws == tsrc) break;                       // scale==1 iterations are state no-ops
        const float wsn   = fminf(tsrc, ws * 2.0f);  // ws_new
        const float ratio = tsrc / ws;               // tsrcs_f / ws (fp32, as in ref)

        // ---- scores (thread-per-candidate full 64-dim dot) ----
        for (int z = tid; z < U; z += 256) {
            int p  = cur[z];
            int tx = (int)rintf((float)p * ratio);
            tx = min(max(tx, 0), TT - 1);
            float s = dotRow64((const float4*)(kh + (size_t)tx * HID), (const float4*)sm.qm);
            sm.skey[z] = orderKey(s);
        }
        // tks = clip(round(ws/tsrc*512), 1, min(ws-1, 1031))
        float tkf = rintf((ws / tsrc) * 512.0f);
        tkf = fminf(fmaxf(tkf, 1.0f), fminf(ws - 1.0f, 1031.0f));
        const int tks = (int)tkf;
        __syncthreads();

        // ---- threshold = tks-th largest score (radix select, parallel scan) ----
        unsigned thr = 0u;                           // tks >= U -> select all
        if (tks < U) {
            if (tid == 0) { sm.scal[0] = tks; sm.scal[1] = 0; }
            __syncthreads();
            for (int bs = 24; bs >= 0; bs -= 8) {
                sm.hist[tid] = 0;
                __syncthreads();
                const unsigned pref = (unsigned)sm.scal[1];
                for (int z = tid; z < U; z += 256) {
                    unsigned key = sm.skey[z];
                    bool ok = (bs == 24) || ((key >> (bs + 8)) == (pref >> (bs + 8)));
                    if (ok) atomicAdd(&sm.hist[(key >> bs) & 255u], 1u);
                }
                __syncthreads();
                if (wave == 0) {
                    // 64-lane parallel suffix/crossing search over 256 buckets
                    int c0 = (int)sm.hist[4*lane+0], c1 = (int)sm.hist[4*lane+1];
                    int c2 = (int)sm.hist[4*lane+2], c3 = (int)sm.hist[4*lane+3];
                    int tsum = c0 + c1 + c2 + c3;
                    int x = tsum;
#pragma unroll
                    for (int o = 1; o < 64; o <<= 1) {
                        int y = __shfl_up(x, o, 64);
                        if (lane >= o) x += y;
                    }
                    const int T   = __shfl(x, 63, 64);
                    const int wnt = sm.scal[0];
                    const int R   = T - wnt;            // crossing b: P(b) > R && P(b)-c(b) <= R
                    int p3 = x, p2 = p3 - c3, p1 = p2 - c2, p0 = p1 - c1, pm1 = p0 - c0;
                    int b = -1, nw = 0, cc = 0;
                    if      (p0 > R && pm1 <= R) { b = 4*lane+0; nw = p0 - R; cc = c0; }
                    else if (p1 > R && p0  <= R) { b = 4*lane+1; nw = p1 - R; cc = c1; }
                    else if (p2 > R && p1  <= R) { b = 4*lane+2; nw = p2 - R; cc = c2; }
                    else if (p3 > R && p2  <= R) { b = 4*lane+3; nw = p3 - R; cc = c3; }
                    if (b >= 0) {
                        sm.scal[0] = nw;
                        sm.scal[1] = (int)(pref | ((unsigned)b << bs));
                        sm.scal[2] = cc;
                    }
                }
                __syncthreads();
                if (sm.scal[2] == sm.scal[0]) break;   // bucket exactly filled -> thr has zero low bits
            }
            thr = (unsigned)sm.scal[1];
        }

        // ---- subdivision into active-window bitmap ----
        const float scale = wsn / ws;
        const int pmax_new = min(32767, (int)rintf((float)(pmaxb + 1) * scale));
        const int nwords = (pmax_new >> 5) + 1;
        for (int w0 = tid; w0 < nwords; w0 += 256) sm.bitmap[w0] = 0;
        __syncthreads();
        for (int z = tid; z < ZC; z += 256) {
            int p = cur[z];
            float pf = (float)p;
            int ps0 = (int)rintf(pf * scale);
            ps0 = min(ps0, 32767);
            atomicOr(&sm.bitmap[ps0 >> 5], 1u << (ps0 & 31));
            if (z < U && sm.skey[z] >= thr) {        // selected -> second child when counts>=2
                int ps1 = (int)rintf((pf + 1.0f) * scale);
                if (ps1 - ps0 >= 2) {
                    int ch = min(ps0 + 1, 32767);
                    atomicOr(&sm.bitmap[ch >> 5], 1u << (ch & 31));
                }
            }
        }
        __syncthreads();

        // ---- compact bitmap -> ascending unique list, capped at ZC ----
        const int base = tid * 4;
        unsigned b0 = (base + 0 < nwords) ? sm.bitmap[base + 0] : 0u;
        unsigned b1 = (base + 1 < nwords) ? sm.bitmap[base + 1] : 0u;
        unsigned b2 = (base + 2 < nwords) ? sm.bitmap[base + 2] : 0u;
        unsigned b3 = (base + 3 < nwords) ? sm.bitmap[base + 3] : 0u;
        int myc = __popc(b0) + __popc(b1) + __popc(b2) + __popc(b3);
        int x = myc;
#pragma unroll
        for (int o = 1; o < 64; o <<= 1) {
            int y = __shfl_up(x, o, 64);
            if (lane >= o) x += y;
        }
        if (lane == 63) sm.wsum[wave] = (unsigned)x;
        __syncthreads();
        int wOff = 0;
        for (int wv = 0; wv < wave; wv++) wOff += (int)sm.wsum[wv];
        const int total = (int)(sm.wsum[0] + sm.wsum[1] + sm.wsum[2] + sm.wsum[3]);
        const int newU = min(total, ZC);
        int pos = wOff + x - myc;
#pragma unroll
        for (int w0 = 0; w0 < 4; w0++) {
            unsigned bits = (w0 == 0) ? b0 : (w0 == 1) ? b1 : (w0 == 2) ? b2 : b3;
            int vbase = (base + w0) << 5;
            while (bits) {
                int b = __ffs(bits) - 1;
                bits &= bits - 1;
                if (pos < ZC) nxt[pos] = (unsigned short)(vbase + b);
                pos++;
            }
        }
        for (int z = newU + tid; z < ZC; z += 256) nxt[z] = 0;
        __syncthreads();

        unsigned short* tmp = cur; cur = nxt; nxt = tmp;
        U = newU;
        ws = wsn;
        pmaxb = pmax_new;
    }

    // ---- attended keys = prefix of cur with value < tsrc (ascending list) ----
    int ca = 0;
    for (int z = tid; z < U; z += 256) ca += (cur[z] < tsrci) ? 1 : 0;
    ca = waveSumI(ca);
    if (lane == 0) sm.scal[wave] = ca;
    __syncthreads();
    const int Uatt = sm.scal[0] + sm.scal[1] + sm.scal[2] + sm.scal[3];
    __syncthreads();

    float* f = (float*)sm.skey;
    for (int z = tid; z < Uatt; z += 256)
        f[z] = dotRow64((const float4*)(kh + (size_t)cur[z] * HID), (const float4*)sm.qf);
    __syncthreads();
    float m = -3.0e38f;
    for (int z = tid; z < Uatt; z += 256) m = fmaxf(m, f[z]);
    m = waveMax(m);
    if (lane == 0) sm.red[wave] = m;
    __syncthreads();
    m = fmaxf(fmaxf(sm.red[0], sm.red[1]), fmaxf(sm.red[2], sm.red[3]));
    __syncthreads();
    float ls = 0.f;
    for (int z = tid; z < Uatt; z += 256) { float e = expf(f[z] - m); f[z] = e; ls += e; }
    ls = waveSum(ls);
    if (lane == 0) sm.red[4 + wave] = ls;
    __syncthreads();
    ls = sm.red[4] + sm.red[5] + sm.red[6] + sm.red[7];
    float4 acc = {0.f, 0.f, 0.f, 0.f};
    for (int z = (wave << 2) + grp; z < Uatt; z += 16) {
        float w = f[z];
        const float4 vv = *reinterpret_cast<const float4*>(vh + (size_t)cur[z] * HID + (sub << 2));
        acc.x = fmaf(w, vv.x, acc.x); acc.y = fmaf(w, vv.y, acc.y);
        acc.z = fmaf(w, vv.z, acc.z); acc.w = fmaf(w, vv.w, acc.w);
    }
#pragma unroll
    for (int o = 16; o <= 32; o <<= 1) {
        acc.x += __shfl_xor(acc.x, o, 64); acc.y += __shfl_xor(acc.y, o, 64);
        acc.z += __shfl_xor(acc.z, o, 64); acc.w += __shfl_xor(acc.w, o, 64);
    }
    if (grp == 0) reinterpret_cast<float4*>(sm.partial)[wave * 16 + sub] = acc;
    __syncthreads();
    if (tid < HID) {
        float o = sm.partial[tid] + sm.partial[64 + tid] + sm.partial[128 + tid] + sm.partial[192 + tid];
        orow[tid] = o / ls;
    }
}

extern "C" void kernel_launch(void* const* d_in, const int* in_sizes, int n_in,
                              void* d_out, int out_size, void* d_ws, size_t ws_size,
                              hipStream_t stream) {
    (void)in_sizes; (void)n_in; (void)d_ws; (void)ws_size; (void)out_size;
    const float* q = (const float*)d_in[0];
    const float* k = (const float*)d_in[1];
    const float* v = (const float*)d_in[2];
    // d_in[3] = mask: analytically causal, not needed
    float* out = (float*)d_out;
    dim3 grid(TT, NHEAD);
    tree_attn_kernel<<<grid, 256, 0, stream>>>(q, k, v, out);
}